// Round 3
// baseline (263.120 us; speedup 1.0000x reference)
//
#include <hip/hip_runtime.h>

// ---- problem constants ----
// B=2, S=1024, P=1024, D=2048, H=16, DH=128, T=P+S=2048
#define SOFT_SCALE 0.08838834764831845f   // 1/sqrt(128)
#define BSD 4194304                        // B*S*D
#define NELEM 4194304                      // elements per [B,S,D] tensor

typedef __attribute__((ext_vector_type(4))) float    f32x4;
typedef __attribute__((ext_vector_type(8))) short    bf16x8;
typedef __attribute__((ext_vector_type(4))) short    bf16x4;
typedef __attribute__((ext_vector_type(4))) unsigned u32x4;

__device__ __forceinline__ float bs2f(short s) {
    unsigned u = ((unsigned)(unsigned short)s) << 16;
    return __builtin_bit_cast(float, u);
}
__device__ __forceinline__ short f2bs(float f) {
    unsigned u = __builtin_bit_cast(unsigned, f);
    unsigned r = (u + 0x7fffu + ((u >> 16) & 1u)) >> 16;
    return (short)r;
}

// async global->LDS, 16B per lane (wave-uniform LDS base + lane*16)
__device__ __forceinline__ void stage16(const short* g, short* l) {
#if __has_builtin(__builtin_amdgcn_global_load_lds)
    __builtin_amdgcn_global_load_lds(
        (const __attribute__((address_space(1))) void*)g,
        (__attribute__((address_space(3))) void*)l, 16, 0, 0);
#else
    *(bf16x8*)l = *(const bf16x8*)g;
#endif
}

// ---------------------------------------------------------------------------
// probe: decide whether past_k_q device buffer is int32 or int8, init scalars
// ---------------------------------------------------------------------------
__global__ void probe_init(const int* __restrict__ q, float* __restrict__ scal) {
    const int lane = threadIdx.x;
    int bad = 0;
#pragma unroll
    for (int i = 0; i < 4; ++i) {
        const int v = q[i * 64 + lane];
        bad |= (v < -128 || v > 127) ? 1 : 0;
    }
    const int anybad = __any(bad);
    if (lane == 0) ((int*)scal)[2] = anybad ? 0 : 1;  // 1 => int32, 0 => int8
    if (lane == 1) scal[0] = 0.f;
    if (lane == 2) scal[1] = 0.f;
}

// ---------------------------------------------------------------------------
// f32 -> bf16 elementwise (hidden_states)
// ---------------------------------------------------------------------------
__global__ void conv_bf16(const float* __restrict__ X, short* __restrict__ Y) {
    const int stride = gridDim.x * blockDim.x;
    for (int i = blockIdx.x * blockDim.x + threadIdx.x; i < NELEM / 8; i += stride) {
        const int e = i * 8;
        f32x4 a = *(const f32x4*)&X[e];
        f32x4 b = *(const f32x4*)&X[e + 4];
        bf16x8 o;
        o[0] = f2bs(a[0]); o[1] = f2bs(a[1]); o[2] = f2bs(a[2]); o[3] = f2bs(a[3]);
        o[4] = f2bs(b[0]); o[5] = f2bs(b[1]); o[6] = f2bs(b[2]); o[7] = f2bs(b[3]);
        *(bf16x8*)&Y[e] = o;
    }
}

// ---------------------------------------------------------------------------
// W[k][n] f32 -> WT[n][k] bf16, up to 3 weights batched over grid.z
// ---------------------------------------------------------------------------
__global__ __launch_bounds__(256) void transpose_conv(const float* __restrict__ W0,
                                                      const float* __restrict__ W1,
                                                      const float* __restrict__ W2,
                                                      short* __restrict__ WT) {
    __shared__ __align__(16) short Tl[64 * 68];
    const float* W = blockIdx.z == 0 ? W0 : (blockIdx.z == 1 ? W1 : W2);
    short* out = WT + (long)blockIdx.z * 4194304;
    const int tid = threadIdx.x;
    const int n0 = blockIdx.x * 64, k0 = blockIdx.y * 64;
#pragma unroll
    for (int i = 0; i < 4; ++i) {
        const int e = i * 1024 + tid * 4;
        const int r = e >> 6, c = e & 63;
        f32x4 f = *(const f32x4*)&W[(long)(k0 + r) * 2048 + n0 + c];
        bf16x4 s4 = { f2bs(f[0]), f2bs(f[1]), f2bs(f[2]), f2bs(f[3]) };
        *(bf16x4*)&Tl[r * 68 + c] = s4;
    }
    __syncthreads();
#pragma unroll
    for (int i = 0; i < 4; ++i) {
        const int e = i * 1024 + tid * 4;
        const int nr = e >> 6, kk = e & 63;
        bf16x4 o = { Tl[(kk + 0) * 68 + nr], Tl[(kk + 1) * 68 + nr],
                     Tl[(kk + 2) * 68 + nr], Tl[(kk + 3) * 68 + nr] };
        *(bf16x4*)&out[(long)(n0 + nr) * 2048 + k0 + kk] = o;
    }
}

// ---------------------------------------------------------------------------
// dequantize past cache into K_full/V_full rows [b*2048 .. b*2048+1024)
// ---------------------------------------------------------------------------
__global__ void dequant_kernel(const void* __restrict__ pk, const void* __restrict__ pv,
                               const float* __restrict__ psk, const float* __restrict__ psv,
                               short* __restrict__ Kf, short* __restrict__ Vf,
                               const int* __restrict__ wsflag) {
    const int z = blockIdx.z;
    const void* src = z ? pv : pk;
    const float sc = z ? *psv : *psk;
    short* dst = z ? Vf : Kf;
    const int flag = wsflag[2];
    const int stride = gridDim.x * blockDim.x;
    for (int i = blockIdx.x * blockDim.x + threadIdx.x; i < NELEM / 8; i += stride) {
        const int e = i * 8;
        int vals[8];
        if (flag) {
            const int* s = (const int*)src + e;
            *(int4*)&vals[0] = *(const int4*)&s[0];
            *(int4*)&vals[4] = *(const int4*)&s[4];
        } else {
            const int2 wv = *(const int2*)((const char*)src + e);
#pragma unroll
            for (int j = 0; j < 4; ++j) vals[j] = (int)(signed char)(wv.x >> (8 * j));
#pragma unroll
            for (int j = 0; j < 4; ++j) vals[4 + j] = (int)(signed char)(wv.y >> (8 * j));
        }
        bf16x8 o;
#pragma unroll
        for (int j = 0; j < 8; ++j) o[j] = f2bs((float)vals[j] * sc);
        *(bf16x8*)&dst[e + ((e >> 21) << 21)] = o;
    }
}

// ---------------------------------------------------------------------------
// GEMM: C = A * Bt^T + bias. 128x128 tile, BK=32, 4-deep LDS pipeline with
// counted vmcnt (T4), source-side XOR granule swizzle (T2, rule #21).
// grid.z==3 => batched QKV (z0: Q bf16*SOFT_SCALE, z1/z2: K/V concat + amax).
// mode: 0 = f32 plain, 1 = bf16 plain, 2 = bf16 concat row-remap
// ---------------------------------------------------------------------------
__global__ __launch_bounds__(256, 2) void gemm_m97(
    const short* __restrict__ A,
    const short* __restrict__ Bt0, const short* __restrict__ Bt1, const short* __restrict__ Bt2,
    const float* __restrict__ bi0, const float* __restrict__ bi1, const float* __restrict__ bi2,
    void* __restrict__ o0, void* __restrict__ o1, void* __restrict__ o2,
    float* __restrict__ scal, int mode_sgl, float scale_sgl, int amax_sgl) {
    __shared__ __align__(16) short Al[4][4096];
    __shared__ __align__(16) short Bl[4][4096];
    const int nbx = gridDim.x, nby = gridDim.y, nbz = gridDim.z;
    const int nwg = nbx * nby * nbz;
    const int orig = blockIdx.x + nbx * (blockIdx.y + nby * blockIdx.z);
    const int cpx = nwg >> 3;
    int swz = (orig & 7) * cpx + (orig >> 3);      // XCD swizzle (nwg % 8 == 0)
    const int bx = swz % nbx; swz /= nbx;
    const int by = swz % nby;
    const int bz = swz / nby;

    const short* Bt   = bz == 0 ? Bt0 : (bz == 1 ? Bt1 : Bt2);
    const float* bias = bz == 0 ? bi0 : (bz == 1 ? bi1 : bi2);
    void* outp        = bz == 0 ? o0  : (bz == 1 ? o1  : o2);
    int mode, amx; float scl;
    if (nbz == 3) { mode = (bz == 0) ? 1 : 2; scl = (bz == 0) ? SOFT_SCALE : 1.f;
                    amx = (bz == 0) ? -1 : (bz - 1); }
    else          { mode = mode_sgl; scl = scale_sgl; amx = amax_sgl; }

    const int tid = threadIdx.x, lane = tid & 63, w = tid >> 6;
    const int wm = w >> 1, wn = w & 1, l4 = lane >> 4, ln = lane & 15;
    const int m0 = by * 128, n0 = bx * 128;

    // staging: thread -> (row = tid>>2, slot = tid&3); source granule XOR-swizzled
    const int srow = tid >> 2;
    const int cswz = ((tid & 3) ^ ((srow >> 1) & 3)) * 8;
    const short* gA0 = A  + (long)(m0 + srow) * 2048 + cswz;
    const short* gA1 = gA0 + 64 * 2048;
    const short* gB0 = Bt + (long)(n0 + srow) * 2048 + cswz;
    const short* gB1 = gB0 + 64 * 2048;

    f32x4 acc[4][4];
#pragma unroll
    for (int mi = 0; mi < 4; ++mi)
#pragma unroll
        for (int ni = 0; ni < 4; ++ni) acc[mi][ni] = (f32x4){0, 0, 0, 0};

#define STAGE_G(buf, ko)                                   \
    do {                                                   \
        stage16(gA0 + (ko), &Al[buf][tid * 8]);            \
        stage16(gA1 + (ko), &Al[buf][2048 + tid * 8]);     \
        stage16(gB0 + (ko), &Bl[buf][tid * 8]);            \
        stage16(gB1 + (ko), &Bl[buf][2048 + tid * 8]);     \
    } while (0)

    STAGE_G(0, 0);
    STAGE_G(1, 32);
    STAGE_G(2, 64);

    const int gsw = (ln >> 1) & 3;   // read-side granule XOR (row>>1)&3 == (ln>>1)&3
    for (int kt = 0; kt < 64; ++kt) {
        if (kt < 62)      asm volatile("s_waitcnt vmcnt(8)" ::: "memory");
        else if (kt == 62) asm volatile("s_waitcnt vmcnt(4)" ::: "memory");
        else               asm volatile("s_waitcnt vmcnt(0)" ::: "memory");
        asm volatile("s_waitcnt lgkmcnt(0)" ::: "memory");
        __builtin_amdgcn_s_barrier();
        if (kt < 61) STAGE_G((kt + 3) & 3, (kt + 3) * 32);
        const int cur = kt & 3;
        bf16x8 af[4], bfr[4];
#pragma unroll
        for (int mi = 0; mi < 4; ++mi)
            af[mi] = *(const bf16x8*)&Al[cur][(wm * 64 + mi * 16 + ln) * 32 + (l4 ^ gsw) * 8];
#pragma unroll
        for (int ni = 0; ni < 4; ++ni)
            bfr[ni] = *(const bf16x8*)&Bl[cur][(wn * 64 + ni * 16 + ln) * 32 + (l4 ^ gsw) * 8];
        __builtin_amdgcn_s_setprio(1);
#pragma unroll
        for (int mi = 0; mi < 4; ++mi)
#pragma unroll
            for (int ni = 0; ni < 4; ++ni)
                acc[mi][ni] = __builtin_amdgcn_mfma_f32_16x16x32_bf16(
                    af[mi], bfr[ni], acc[mi][ni], 0, 0, 0);
        __builtin_amdgcn_s_setprio(0);
    }
#undef STAGE_G

    float amax = 0.f;
#pragma unroll
    for (int ni = 0; ni < 4; ++ni) {
        const int gn = n0 + wn * 64 + ni * 16 + ln;
        const float bv = bias[gn];
#pragma unroll
        for (int mi = 0; mi < 4; ++mi) {
#pragma unroll
            for (int r = 0; r < 4; ++r) {
                const int gm = m0 + wm * 64 + mi * 16 + l4 * 4 + r;
                const float v = (acc[mi][ni][r] + bv) * scl;
                amax = fmaxf(amax, fabsf(v));
                if (mode == 0) {
                    ((float*)outp)[(long)gm * 2048 + gn] = v;
                } else if (mode == 1) {
                    ((short*)outp)[(long)gm * 2048 + gn] = f2bs(v);
                } else {
                    const int gr = gm + 1024 + ((gm >> 10) << 10);  // b*2048+1024+s
                    ((short*)outp)[(long)gr * 2048 + gn] = f2bs(v);
                }
            }
        }
    }
    if (amx >= 0) {
#pragma unroll
        for (int o = 32; o > 0; o >>= 1) amax = fmaxf(amax, __shfl_xor(amax, o));
        if (lane == 0)
            atomicMax((unsigned int*)&scal[amx], __builtin_bit_cast(unsigned int, amax));
    }
}

// ---------------------------------------------------------------------------
// quantize new-KV region -> d_out (as floats), plus the two scale scalars
// ---------------------------------------------------------------------------
__global__ void quantize_kernel(const short* __restrict__ Kf, const short* __restrict__ Vf,
                                const float* __restrict__ scal, float* __restrict__ out) {
    const int z = blockIdx.z;
    const short* src = z ? Vf : Kf;
    const float mx = scal[z];
    const float scale = mx * (1.f / 127.f);
    const float inv = (mx > 0.f) ? 127.f / mx : 0.f;
    const long ob = z ? (2L * BSD + 1) : (1L * BSD);
    if (blockIdx.x == 0 && threadIdx.x == 0)
        out[z ? (3L * BSD + 1) : (2L * BSD)] = scale;
    const int stride = gridDim.x * blockDim.x;
    for (int i = blockIdx.x * blockDim.x + threadIdx.x; i < NELEM / 4; i += stride) {
        const int e = i * 4;
        const int flat = e + 2097152 + ((e >> 21) << 21);
        bf16x4 x4 = *(const bf16x4*)&src[flat];
        float4 q;
        q.x = fminf(127.f, fmaxf(-128.f, rintf(bs2f(x4[0]) * inv)));
        q.y = fminf(127.f, fmaxf(-128.f, rintf(bs2f(x4[1]) * inv)));
        q.z = fminf(127.f, fmaxf(-128.f, rintf(bs2f(x4[2]) * inv)));
        q.w = fminf(127.f, fmaxf(-128.f, rintf(bs2f(x4[3]) * inv)));
        *(float4*)&out[ob + e] = q;
    }
}

// ---------------------------------------------------------------------------
// flash attention. Block decode groups 4 (b,h) pairs per XCD (L2-resident KV)
// and pairs complementary qt on the same CU. Q pre-scaled by 1/sqrt(DH).
// T13 defer-max; causal mask only on tiles t>=16.
// ---------------------------------------------------------------------------
__global__ __launch_bounds__(256, 2) void attn_kernel(const short* __restrict__ Q,
                                                      const short* __restrict__ Kf,
                                                      const short* __restrict__ Vf,
                                                      short* __restrict__ O) {
    __shared__ __align__(16) short Kl[64 * 136];
    __shared__ __align__(16) short Vt[128 * 72];
    // decode: XCD x = L&7 gets pairs {x, x+8, x+16, x+24}; qt flipped for pgrp>=2
    const int L = blockIdx.x + 16 * (blockIdx.y + 16 * blockIdx.z);
    const int x = L & 7, rr = L >> 3;
    const int qt0 = rr & 15, pgrp = rr >> 4;
    const int p = x + 8 * pgrp;
    const int h = p >> 1, b = p & 1;
    const int qt = (pgrp >= 2) ? (15 - qt0) : qt0;

    const int tid = threadIdx.x, w = tid >> 6, lane = tid & 63;
    const int l4 = lane >> 4, n = lane & 15;
    const int rg = tid >> 4, cg = tid & 15, stc = cg * 8;
    const int sIdx = qt * 64 + w * 16 + n;
    const int qlim = 1024 + sIdx;

    bf16x8 qf[4];
#pragma unroll
    for (int c = 0; c < 4; ++c)
        qf[c] = *(const bf16x8*)&Q[(long)(b * 1024 + sIdx) * 2048 + h * 128 + c * 32 + l4 * 8];

    f32x4 acco[8];
#pragma unroll
    for (int i = 0; i < 8; ++i) acco[i] = (f32x4){0, 0, 0, 0};
    float m_run = -1e30f, l_run = 0.f;

    const short* Kb = Kf + (long)(b * 2048) * 2048 + h * 128;
    const short* Vb = Vf + (long)(b * 2048) * 2048 + h * 128;
    const int nt = 17 + qt;

    bf16x8 kreg[4], vreg[4];
#pragma unroll
    for (int i = 0; i < 4; ++i) kreg[i] = *(const bf16x8*)&Kb[(long)(i * 16 + rg) * 2048 + stc];
#pragma unroll
    for (int i = 0; i < 4; ++i) vreg[i] = *(const bf16x8*)&Vb[(long)(rg * 4 + i) * 2048 + stc];

    for (int t = 0; t < nt; ++t) {
        const int t0 = t * 64;
        __syncthreads();
#pragma unroll
        for (int i = 0; i < 4; ++i)
            *(bf16x8*)&Kl[(i * 16 + rg) * 136 + stc] = kreg[i];
#pragma unroll
        for (int j = 0; j < 8; ++j) {
            const int d = stc + j;
            bf16x4 c4 = { vreg[0][j], vreg[1][j], vreg[2][j], vreg[3][j] };
            *(bf16x4*)&Vt[d * 72 + ((rg ^ ((d >> 3) & 7)) << 2)] = c4;
        }
        if (t + 1 < nt) {
            const int t1 = (t + 1) * 64;
#pragma unroll
            for (int i = 0; i < 4; ++i)
                kreg[i] = *(const bf16x8*)&Kb[(long)(t1 + i * 16 + rg) * 2048 + stc];
#pragma unroll
            for (int i = 0; i < 4; ++i)
                vreg[i] = *(const bf16x8*)&Vb[(long)(t1 + rg * 4 + i) * 2048 + stc];
        }
        __syncthreads();

        // QK^T (scores^T): lane holds 16 p-values for q-row sIdx
        float p16[16];
        __builtin_amdgcn_s_setprio(1);
#pragma unroll
        for (int kt = 0; kt < 4; ++kt) {
            f32x4 sc4 = (f32x4){0, 0, 0, 0};
#pragma unroll
            for (int c = 0; c < 4; ++c) {
                bf16x8 kfr = *(const bf16x8*)&Kl[(kt * 16 + n) * 136 + c * 32 + l4 * 8];
                sc4 = __builtin_amdgcn_mfma_f32_16x16x32_bf16(kfr, qf[c], sc4, 0, 0, 0);
            }
#pragma unroll
            for (int r = 0; r < 4; ++r) p16[kt * 4 + r] = sc4[r];
        }
        __builtin_amdgcn_s_setprio(0);
        if (t >= 16) {   // causal masking only needed past the cache region
#pragma unroll
            for (int i = 0; i < 16; ++i) {
                const int kg = t0 + (i >> 2) * 16 + l4 * 4 + (i & 3);
                if (kg > qlim) p16[i] = -1e30f;
            }
        }

        float tmax = p16[0];
#pragma unroll
        for (int i = 1; i < 16; ++i) tmax = fmaxf(tmax, p16[i]);
        tmax = fmaxf(tmax, __shfl_xor(tmax, 16));
        tmax = fmaxf(tmax, __shfl_xor(tmax, 32));
        if (!__all(tmax <= m_run + 8.f)) {      // T13 defer-max
            const float mnew = fmaxf(m_run, tmax);
            const float fac = __expf(m_run - mnew);
            l_run *= fac;
#pragma unroll
            for (int i = 0; i < 8; ++i) acco[i] *= fac;
            m_run = mnew;
        }
        float tsum = 0.f;
#pragma unroll
        for (int i = 0; i < 16; ++i) { p16[i] = __expf(p16[i] - m_run); tsum += p16[i]; }
        tsum += __shfl_xor(tsum, 16);
        tsum += __shfl_xor(tsum, 32);
        l_run += tsum;

        // P -> bf16 via v_cvt_pk_bf16_f32 (RNE), same element order as before
        u32x4 pw0, pw1;
#pragma unroll
        for (int wd = 0; wd < 4; ++wd) {
            unsigned r0, r1;
            asm("v_cvt_pk_bf16_f32 %0, %1, %2" : "=v"(r0) : "v"(p16[2 * wd]), "v"(p16[2 * wd + 1]));
            asm("v_cvt_pk_bf16_f32 %0, %1, %2" : "=v"(r1) : "v"(p16[8 + 2 * wd]), "v"(p16[8 + 2 * wd + 1]));
            pw0[wd] = r0; pw1[wd] = r1;
        }
        bf16x8 pb[2] = { __builtin_bit_cast(bf16x8, pw0), __builtin_bit_cast(bf16x8, pw1) };

        __builtin_amdgcn_s_setprio(1);
#pragma unroll
        for (int dc = 0; dc < 8; ++dc) {
            const int d = dc * 16 + n;
            const int swd = ((d >> 3) & 7) << 2;
#pragma unroll
            for (int k32 = 0; k32 < 2; ++k32) {
                bf16x4 g0 = *(const bf16x4*)&Vt[d * 72 + (k32 * 32 + ((4 * l4) ^ swd))];
                bf16x4 g1 = *(const bf16x4*)&Vt[d * 72 + (k32 * 32 + ((16 + 4 * l4) ^ swd))];
                bf16x8 vf = { g0[0], g0[1], g0[2], g0[3], g1[0], g1[1], g1[2], g1[3] };
                acco[dc] = __builtin_amdgcn_mfma_f32_16x16x32_bf16(vf, pb[k32], acco[dc], 0, 0, 0);
            }
        }
        __builtin_amdgcn_s_setprio(0);
    }

    __syncthreads();
    const float inv = 1.f / l_run;
#pragma unroll
    for (int dc = 0; dc < 8; ++dc)
#pragma unroll
        for (int r = 0; r < 4; ++r)
            Kl[(w * 16 + n) * 136 + dc * 16 + l4 * 4 + r] = f2bs(acco[dc][r] * inv);
    __syncthreads();
#pragma unroll
    for (int i = 0; i < 4; ++i) {
        const int row = i * 4 + (lane >> 4);
        const int col = (lane & 15) * 8;
        bf16x8 ov = *(const bf16x8*)&Kl[(w * 16 + row) * 136 + col];
        *(bf16x8*)&O[(long)(b * 1024 + qt * 64 + w * 16 + row) * 2048 + h * 128 + col] = ov;
    }
}

// ---------------------------------------------------------------------------
extern "C" void kernel_launch(void* const* d_in, const int* in_sizes, int n_in,
                              void* d_out, int out_size, void* d_ws, size_t ws_size,
                              hipStream_t stream) {
    const float* h   = (const float*)d_in[0];
    const float* Wq  = (const float*)d_in[1];
    const float* bq  = (const float*)d_in[2];
    const float* Wk  = (const float*)d_in[3];
    const float* bk  = (const float*)d_in[4];
    const float* Wv  = (const float*)d_in[5];
    const float* bv  = (const float*)d_in[6];
    const float* Wo  = (const float*)d_in[7];
    const float* bo  = (const float*)d_in[8];
    const void*  pkq = d_in[9];
    const float* pks = (const float*)d_in[10];
    const void*  pvq = d_in[11];
    const float* pvs = (const float*)d_in[12];
    float* out = (float*)d_out;

    char* ws = (char*)d_ws;
    dim3 blk(256);
    const bool big = (ws_size >= 75500000ull);

    if (big) {
        float* scal  = (float*)ws;
        short* hbf   = (short*)(ws + 256);                       // 8.4MB (reused as attn out)
        short* WT3   = (short*)(ws + 256 + 1L * 8388608);        // 25.2MB (3 transposed weights)
        short* Qbf   = (short*)(ws + 256 + 4L * 8388608);        // 8.4MB
        short* Kfull = (short*)(ws + 256 + 5L * 8388608);        // 16.8MB
        short* Vfull = (short*)(ws + 256 + 5L * 8388608 + 16777216);
        short* attnb = hbf;

        probe_init<<<1, 64, 0, stream>>>((const int*)pkq, scal);
        conv_bf16<<<1024, blk, 0, stream>>>(h, hbf);
        dequant_kernel<<<dim3(256, 1, 2), blk, 0, stream>>>(pkq, pvq, pks, pvs, Kfull, Vfull,
                                                            (const int*)d_ws);
        transpose_conv<<<dim3(32, 32, 3), blk, 0, stream>>>(Wq, Wk, Wv, WT3);
        gemm_m97<<<dim3(16, 16, 3), blk, 0, stream>>>(hbf, WT3, WT3 + 4194304, WT3 + 8388608,
                                                      bq, bk, bv, Qbf, Kfull, Vfull,
                                                      scal, 0, 1.f, -1);
        quantize_kernel<<<dim3(256, 1, 2), blk, 0, stream>>>(Kfull, Vfull, scal, out);
        attn_kernel<<<dim3(16, 16, 2), blk, 0, stream>>>(Qbf, Kfull, Vfull, attnb);
        transpose_conv<<<dim3(32, 32, 1), blk, 0, stream>>>(Wo, Wo, Wo, WT3);
        gemm_m97<<<dim3(16, 16, 1), blk, 0, stream>>>(attnb, WT3, WT3, WT3, bo, bo, bo,
                                                      out, out, out, scal, 0, 1.f, -1);
    } else {
        float* scal  = (float*)ws;
        short* hbf   = (short*)(ws + 256);
        short* WT    = (short*)(ws + 256 + 1L * 8388608);
        short* Qbf   = (short*)(ws + 256 + 2L * 8388608);
        short* Kfull = (short*)(ws + 256 + 3L * 8388608);
        short* Vfull = (short*)(ws + 256 + 3L * 8388608 + 16777216);
        short* attnb = hbf;

        probe_init<<<1, 64, 0, stream>>>((const int*)pkq, scal);
        conv_bf16<<<1024, blk, 0, stream>>>(h, hbf);
        dequant_kernel<<<dim3(256, 1, 2), blk, 0, stream>>>(pkq, pvq, pks, pvs, Kfull, Vfull,
                                                            (const int*)d_ws);
        transpose_conv<<<dim3(32, 32, 1), blk, 0, stream>>>(Wk, Wk, Wk, WT);
        gemm_m97<<<dim3(16, 16, 1), blk, 0, stream>>>(hbf, WT, WT, WT, bk, bk, bk,
                                                      Kfull, Kfull, Kfull, scal, 2, 1.f, 0);
        transpose_conv<<<dim3(32, 32, 1), blk, 0, stream>>>(Wv, Wv, Wv, WT);
        gemm_m97<<<dim3(16, 16, 1), blk, 0, stream>>>(hbf, WT, WT, WT, bv, bv, bv,
                                                      Vfull, Vfull, Vfull, scal, 2, 1.f, 1);
        quantize_kernel<<<dim3(256, 1, 2), blk, 0, stream>>>(Kfull, Vfull, scal, out);
        transpose_conv<<<dim3(32, 32, 1), blk, 0, stream>>>(Wq, Wq, Wq, WT);
        gemm_m97<<<dim3(16, 16, 1), blk, 0, stream>>>(hbf, WT, WT, WT, bq, bq, bq,
                                                      Qbf, Qbf, Qbf, scal, 1, SOFT_SCALE, -1);
        attn_kernel<<<dim3(16, 16, 2), blk, 0, stream>>>(Qbf, Kfull, Vfull, attnb);
        transpose_conv<<<dim3(32, 32, 1), blk, 0, stream>>>(Wo, Wo, Wo, WT);
        gemm_m97<<<dim3(16, 16, 1), blk, 0, stream>>>(attnb, WT, WT, WT, bo, bo, bo,
                                                      out, out, out, scal, 0, 1.f, -1);
    }
}

// Round 4
// 229.566 us; speedup vs baseline: 1.1462x; 1.1462x over previous
//
#include <hip/hip_runtime.h>

// ---- problem constants ----
// B=2, S=1024, P=1024, D=2048, H=16, DH=128, T=P+S=2048
#define SOFT_SCALE 0.08838834764831845f   // 1/sqrt(128)
#define BSD 4194304                        // B*S*D
#define NELEM 4194304                      // elements per [B,S,D] tensor

typedef __attribute__((ext_vector_type(4))) float    f32x4;
typedef __attribute__((ext_vector_type(8))) short    bf16x8;
typedef __attribute__((ext_vector_type(4))) short    bf16x4;
typedef __attribute__((ext_vector_type(4))) unsigned u32x4;

__device__ __forceinline__ float bs2f(short s) {
    unsigned u = ((unsigned)(unsigned short)s) << 16;
    return __builtin_bit_cast(float, u);
}
__device__ __forceinline__ short f2bs(float f) {
    unsigned u = __builtin_bit_cast(unsigned, f);
    unsigned r = (u + 0x7fffu + ((u >> 16) & 1u)) >> 16;
    return (short)r;
}

// async global->LDS, 16B per lane (wave-uniform LDS base + lane*16)
__device__ __forceinline__ void stage16(const short* g, short* l) {
#if __has_builtin(__builtin_amdgcn_global_load_lds)
    __builtin_amdgcn_global_load_lds(
        (const __attribute__((address_space(1))) void*)g,
        (__attribute__((address_space(3))) void*)l, 16, 0, 0);
#else
    *(bf16x8*)l = *(const bf16x8*)g;
#endif
}

// ---------------------------------------------------------------------------
// probe: decide whether past_k_q device buffer is int32 or int8, init scalars
// ---------------------------------------------------------------------------
__global__ void probe_init(const int* __restrict__ q, float* __restrict__ scal) {
    const int lane = threadIdx.x;
    int bad = 0;
#pragma unroll
    for (int i = 0; i < 4; ++i) {
        const int v = q[i * 64 + lane];
        bad |= (v < -128 || v > 127) ? 1 : 0;
    }
    const int anybad = __any(bad);
    if (lane == 0) ((int*)scal)[2] = anybad ? 0 : 1;  // 1 => int32, 0 => int8
    if (lane == 1) scal[0] = 0.f;
    if (lane == 2) scal[1] = 0.f;
}

// ---------------------------------------------------------------------------
// f32 -> bf16 elementwise (hidden_states)
// ---------------------------------------------------------------------------
__global__ void conv_bf16(const float* __restrict__ X, short* __restrict__ Y) {
    const int stride = gridDim.x * blockDim.x;
    for (int i = blockIdx.x * blockDim.x + threadIdx.x; i < NELEM / 8; i += stride) {
        const int e = i * 8;
        f32x4 a = *(const f32x4*)&X[e];
        f32x4 b = *(const f32x4*)&X[e + 4];
        bf16x8 o;
        o[0] = f2bs(a[0]); o[1] = f2bs(a[1]); o[2] = f2bs(a[2]); o[3] = f2bs(a[3]);
        o[4] = f2bs(b[0]); o[5] = f2bs(b[1]); o[6] = f2bs(b[2]); o[7] = f2bs(b[3]);
        *(bf16x8*)&Y[e] = o;
    }
}

// ---------------------------------------------------------------------------
// W[k][n] f32 -> WT[n][k] bf16, up to 3 weights batched over grid.z
// ---------------------------------------------------------------------------
__global__ __launch_bounds__(256) void transpose_conv(const float* __restrict__ W0,
                                                      const float* __restrict__ W1,
                                                      const float* __restrict__ W2,
                                                      short* __restrict__ WT) {
    __shared__ __align__(16) short Tl[64 * 68];
    const float* W = blockIdx.z == 0 ? W0 : (blockIdx.z == 1 ? W1 : W2);
    short* out = WT + (long)blockIdx.z * 4194304;
    const int tid = threadIdx.x;
    const int n0 = blockIdx.x * 64, k0 = blockIdx.y * 64;
#pragma unroll
    for (int i = 0; i < 4; ++i) {
        const int e = i * 1024 + tid * 4;
        const int r = e >> 6, c = e & 63;
        f32x4 f = *(const f32x4*)&W[(long)(k0 + r) * 2048 + n0 + c];
        bf16x4 s4 = { f2bs(f[0]), f2bs(f[1]), f2bs(f[2]), f2bs(f[3]) };
        *(bf16x4*)&Tl[r * 68 + c] = s4;
    }
    __syncthreads();
#pragma unroll
    for (int i = 0; i < 4; ++i) {
        const int e = i * 1024 + tid * 4;
        const int nr = e >> 6, kk = e & 63;
        bf16x4 o = { Tl[(kk + 0) * 68 + nr], Tl[(kk + 1) * 68 + nr],
                     Tl[(kk + 2) * 68 + nr], Tl[(kk + 3) * 68 + nr] };
        *(bf16x4*)&out[(long)(n0 + nr) * 2048 + k0 + kk] = o;
    }
}

// ---------------------------------------------------------------------------
// dequantize past cache into K_full/V_full rows [b*2048 .. b*2048+1024)
// ---------------------------------------------------------------------------
__global__ void dequant_kernel(const void* __restrict__ pk, const void* __restrict__ pv,
                               const float* __restrict__ psk, const float* __restrict__ psv,
                               short* __restrict__ Kf, short* __restrict__ Vf,
                               const int* __restrict__ wsflag) {
    const int z = blockIdx.z;
    const void* src = z ? pv : pk;
    const float sc = z ? *psv : *psk;
    short* dst = z ? Vf : Kf;
    const int flag = wsflag[2];
    const int stride = gridDim.x * blockDim.x;
    for (int i = blockIdx.x * blockDim.x + threadIdx.x; i < NELEM / 8; i += stride) {
        const int e = i * 8;
        int vals[8];
        if (flag) {
            const int* s = (const int*)src + e;
            *(int4*)&vals[0] = *(const int4*)&s[0];
            *(int4*)&vals[4] = *(const int4*)&s[4];
        } else {
            const int2 wv = *(const int2*)((const char*)src + e);
#pragma unroll
            for (int j = 0; j < 4; ++j) vals[j] = (int)(signed char)(wv.x >> (8 * j));
#pragma unroll
            for (int j = 0; j < 4; ++j) vals[4 + j] = (int)(signed char)(wv.y >> (8 * j));
        }
        bf16x8 o;
#pragma unroll
        for (int j = 0; j < 8; ++j) o[j] = f2bs((float)vals[j] * sc);
        *(bf16x8*)&dst[e + ((e >> 21) << 21)] = o;
    }
}

// ---------------------------------------------------------------------------
// GEMM: C = A * Bt^T + bias. 128x128 tile, BK=32, 2-buffer LDS (32KB) with
// 2-deep counted-vmcnt pipeline (never drains to 0 in main loop), source-side
// XOR granule swizzle (T2, rule #21: same involution on source and read).
// grid.z==3 => batched QKV (z0: Q bf16*SOFT_SCALE, z1/z2: K/V concat + amax).
// mode: 0 = f32 plain, 1 = bf16 plain, 2 = bf16 concat row-remap
// ---------------------------------------------------------------------------
__global__ __launch_bounds__(256, 3) void gemm_m97(
    const short* __restrict__ A,
    const short* __restrict__ Bt0, const short* __restrict__ Bt1, const short* __restrict__ Bt2,
    const float* __restrict__ bi0, const float* __restrict__ bi1, const float* __restrict__ bi2,
    void* __restrict__ o0, void* __restrict__ o1, void* __restrict__ o2,
    float* __restrict__ scal, int mode_sgl, float scale_sgl, int amax_sgl) {
    __shared__ __align__(16) short Al[2][4096];
    __shared__ __align__(16) short Bl[2][4096];
    const int nbx = gridDim.x, nby = gridDim.y, nbz = gridDim.z;
    const int nwg = nbx * nby * nbz;
    const int orig = blockIdx.x + nbx * (blockIdx.y + nby * blockIdx.z);
    const int cpx = nwg >> 3;
    int swz = (orig & 7) * cpx + (orig >> 3);      // XCD swizzle (nwg % 8 == 0)
    const int bx = swz % nbx; swz /= nbx;
    const int by = swz % nby;
    const int bz = swz / nby;

    const short* Bt   = bz == 0 ? Bt0 : (bz == 1 ? Bt1 : Bt2);
    const float* bias = bz == 0 ? bi0 : (bz == 1 ? bi1 : bi2);
    void* outp        = bz == 0 ? o0  : (bz == 1 ? o1  : o2);
    int mode, amx; float scl;
    if (nbz == 3) { mode = (bz == 0) ? 1 : 2; scl = (bz == 0) ? SOFT_SCALE : 1.f;
                    amx = (bz == 0) ? -1 : (bz - 1); }
    else          { mode = mode_sgl; scl = scale_sgl; amx = amax_sgl; }

    const int tid = threadIdx.x, lane = tid & 63, w = tid >> 6;
    const int wm = w >> 1, wn = w & 1, l4 = lane >> 4, ln = lane & 15;
    const int m0 = by * 128, n0 = bx * 128;

    // staging: thread -> (row = tid>>2, slot = tid&3); source granule XOR-swizzled
    const int srow = tid >> 2;
    const int cswz = ((tid & 3) ^ ((srow >> 1) & 3)) * 8;
    const short* gA0 = A  + (long)(m0 + srow) * 2048 + cswz;
    const short* gA1 = gA0 + 64 * 2048;
    const short* gB0 = Bt + (long)(n0 + srow) * 2048 + cswz;
    const short* gB1 = gB0 + 64 * 2048;

    f32x4 acc[4][4];
#pragma unroll
    for (int mi = 0; mi < 4; ++mi)
#pragma unroll
        for (int ni = 0; ni < 4; ++ni) acc[mi][ni] = (f32x4){0, 0, 0, 0};

#define STAGE_G(buf, ko)                                   \
    do {                                                   \
        stage16(gA0 + (ko), &Al[buf][tid * 8]);            \
        stage16(gA1 + (ko), &Al[buf][2048 + tid * 8]);     \
        stage16(gB0 + (ko), &Bl[buf][tid * 8]);            \
        stage16(gB1 + (ko), &Bl[buf][2048 + tid * 8]);     \
    } while (0)

    STAGE_G(0, 0);      // 4 loads
    STAGE_G(1, 32);     // 8 loads outstanding

    const int gsw = (ln >> 1) & 3;   // read-side granule XOR: (row>>1)&3 == (ln>>1)&3
    for (int kt = 0; kt < 64; ++kt) {
        // current buffer's 4 loads are the oldest; leave the next buffer's in flight
        if (kt < 63) asm volatile("s_waitcnt vmcnt(4)" ::: "memory");
        else         asm volatile("s_waitcnt vmcnt(0)" ::: "memory");
        __builtin_amdgcn_s_barrier();               // buf[kt&1] visible to all waves
        const int cur = kt & 1;
        bf16x8 af[4], bfr[4];
#pragma unroll
        for (int mi = 0; mi < 4; ++mi)
            af[mi] = *(const bf16x8*)&Al[cur][(wm * 64 + mi * 16 + ln) * 32 + (l4 ^ gsw) * 8];
#pragma unroll
        for (int ni = 0; ni < 4; ++ni)
            bfr[ni] = *(const bf16x8*)&Bl[cur][(wn * 64 + ni * 16 + ln) * 32 + (l4 ^ gsw) * 8];
        asm volatile("s_waitcnt lgkmcnt(0)" ::: "memory");
        __builtin_amdgcn_s_barrier();               // all waves done reading buf[cur]
        if (kt < 62) STAGE_G(cur, (kt + 2) * 32);   // refill just-read buffer
        __builtin_amdgcn_s_setprio(1);
#pragma unroll
        for (int mi = 0; mi < 4; ++mi)
#pragma unroll
            for (int ni = 0; ni < 4; ++ni)
                acc[mi][ni] = __builtin_amdgcn_mfma_f32_16x16x32_bf16(
                    af[mi], bfr[ni], acc[mi][ni], 0, 0, 0);
        __builtin_amdgcn_s_setprio(0);
    }
#undef STAGE_G

    float amax = 0.f;
#pragma unroll
    for (int ni = 0; ni < 4; ++ni) {
        const int gn = n0 + wn * 64 + ni * 16 + ln;
        const float bv = bias[gn];
#pragma unroll
        for (int mi = 0; mi < 4; ++mi) {
#pragma unroll
            for (int r = 0; r < 4; ++r) {
                const int gm = m0 + wm * 64 + mi * 16 + l4 * 4 + r;
                const float v = (acc[mi][ni][r] + bv) * scl;
                amax = fmaxf(amax, fabsf(v));
                if (mode == 0) {
                    ((float*)outp)[(long)gm * 2048 + gn] = v;
                } else if (mode == 1) {
                    ((short*)outp)[(long)gm * 2048 + gn] = f2bs(v);
                } else {
                    const int gr = gm + 1024 + ((gm >> 10) << 10);  // b*2048+1024+s
                    ((short*)outp)[(long)gr * 2048 + gn] = f2bs(v);
                }
            }
        }
    }
    if (amx >= 0) {
#pragma unroll
        for (int o = 32; o > 0; o >>= 1) amax = fmaxf(amax, __shfl_xor(amax, o));
        if (lane == 0)
            atomicMax((unsigned int*)&scal[amx], __builtin_bit_cast(unsigned int, amax));
    }
}

// ---------------------------------------------------------------------------
// quantize new-KV region -> d_out (as floats), plus the two scale scalars
// ---------------------------------------------------------------------------
__global__ void quantize_kernel(const short* __restrict__ Kf, const short* __restrict__ Vf,
                                const float* __restrict__ scal, float* __restrict__ out) {
    const int z = blockIdx.z;
    const short* src = z ? Vf : Kf;
    const float mx = scal[z];
    const float scale = mx * (1.f / 127.f);
    const float inv = (mx > 0.f) ? 127.f / mx : 0.f;
    const long ob = z ? (2L * BSD + 1) : (1L * BSD);
    if (blockIdx.x == 0 && threadIdx.x == 0)
        out[z ? (3L * BSD + 1) : (2L * BSD)] = scale;
    const int stride = gridDim.x * blockDim.x;
    for (int i = blockIdx.x * blockDim.x + threadIdx.x; i < NELEM / 4; i += stride) {
        const int e = i * 4;
        const int flat = e + 2097152 + ((e >> 21) << 21);
        bf16x4 x4 = *(const bf16x4*)&src[flat];
        float4 q;
        q.x = fminf(127.f, fmaxf(-128.f, rintf(bs2f(x4[0]) * inv)));
        q.y = fminf(127.f, fmaxf(-128.f, rintf(bs2f(x4[1]) * inv)));
        q.z = fminf(127.f, fmaxf(-128.f, rintf(bs2f(x4[2]) * inv)));
        q.w = fminf(127.f, fmaxf(-128.f, rintf(bs2f(x4[3]) * inv)));
        *(float4*)&out[ob + e] = q;
    }
}

// ---------------------------------------------------------------------------
// flash attention. Block decode groups 4 (b,h) pairs per XCD (L2-resident KV)
// and pairs complementary qt on the same CU. Q pre-scaled by 1/sqrt(DH).
// T13 defer-max; causal mask only on tiles t>=16.
// ---------------------------------------------------------------------------
__global__ __launch_bounds__(256, 2) void attn_kernel(const short* __restrict__ Q,
                                                      const short* __restrict__ Kf,
                                                      const short* __restrict__ Vf,
                                                      short* __restrict__ O) {
    __shared__ __align__(16) short Kl[64 * 136];
    __shared__ __align__(16) short Vt[128 * 72];
    // decode: XCD x = L&7 gets pairs {x, x+8, x+16, x+24}; qt flipped for pgrp>=2
    const int L = blockIdx.x + 16 * (blockIdx.y + 16 * blockIdx.z);
    const int x = L & 7, rr = L >> 3;
    const int qt0 = rr & 15, pgrp = rr >> 4;
    const int p = x + 8 * pgrp;
    const int h = p >> 1, b = p & 1;
    const int qt = (pgrp >= 2) ? (15 - qt0) : qt0;

    const int tid = threadIdx.x, w = tid >> 6, lane = tid & 63;
    const int l4 = lane >> 4, n = lane & 15;
    const int rg = tid >> 4, cg = tid & 15, stc = cg * 8;
    const int sIdx = qt * 64 + w * 16 + n;
    const int qlim = 1024 + sIdx;

    bf16x8 qf[4];
#pragma unroll
    for (int c = 0; c < 4; ++c)
        qf[c] = *(const bf16x8*)&Q[(long)(b * 1024 + sIdx) * 2048 + h * 128 + c * 32 + l4 * 8];

    f32x4 acco[8];
#pragma unroll
    for (int i = 0; i < 8; ++i) acco[i] = (f32x4){0, 0, 0, 0};
    float m_run = -1e30f, l_run = 0.f;

    const short* Kb = Kf + (long)(b * 2048) * 2048 + h * 128;
    const short* Vb = Vf + (long)(b * 2048) * 2048 + h * 128;
    const int nt = 17 + qt;

    bf16x8 kreg[4], vreg[4];
#pragma unroll
    for (int i = 0; i < 4; ++i) kreg[i] = *(const bf16x8*)&Kb[(long)(i * 16 + rg) * 2048 + stc];
#pragma unroll
    for (int i = 0; i < 4; ++i) vreg[i] = *(const bf16x8*)&Vb[(long)(rg * 4 + i) * 2048 + stc];

    for (int t = 0; t < nt; ++t) {
        const int t0 = t * 64;
        __syncthreads();
#pragma unroll
        for (int i = 0; i < 4; ++i)
            *(bf16x8*)&Kl[(i * 16 + rg) * 136 + stc] = kreg[i];
#pragma unroll
        for (int j = 0; j < 8; ++j) {
            const int d = stc + j;
            bf16x4 c4 = { vreg[0][j], vreg[1][j], vreg[2][j], vreg[3][j] };
            *(bf16x4*)&Vt[d * 72 + ((rg ^ ((d >> 3) & 7)) << 2)] = c4;
        }
        if (t + 1 < nt) {
            const int t1 = (t + 1) * 64;
#pragma unroll
            for (int i = 0; i < 4; ++i)
                kreg[i] = *(const bf16x8*)&Kb[(long)(t1 + i * 16 + rg) * 2048 + stc];
#pragma unroll
            for (int i = 0; i < 4; ++i)
                vreg[i] = *(const bf16x8*)&Vb[(long)(t1 + rg * 4 + i) * 2048 + stc];
        }
        __syncthreads();

        // QK^T (scores^T): lane holds 16 p-values for q-row sIdx
        float p16[16];
        __builtin_amdgcn_s_setprio(1);
#pragma unroll
        for (int kt = 0; kt < 4; ++kt) {
            f32x4 sc4 = (f32x4){0, 0, 0, 0};
#pragma unroll
            for (int c = 0; c < 4; ++c) {
                bf16x8 kfr = *(const bf16x8*)&Kl[(kt * 16 + n) * 136 + c * 32 + l4 * 8];
                sc4 = __builtin_amdgcn_mfma_f32_16x16x32_bf16(kfr, qf[c], sc4, 0, 0, 0);
            }
#pragma unroll
            for (int r = 0; r < 4; ++r) p16[kt * 4 + r] = sc4[r];
        }
        __builtin_amdgcn_s_setprio(0);
        if (t >= 16) {   // causal masking only needed past the cache region
#pragma unroll
            for (int i = 0; i < 16; ++i) {
                const int kg = t0 + (i >> 2) * 16 + l4 * 4 + (i & 3);
                if (kg > qlim) p16[i] = -1e30f;
            }
        }

        float tmax = p16[0];
#pragma unroll
        for (int i = 1; i < 16; ++i) tmax = fmaxf(tmax, p16[i]);
        tmax = fmaxf(tmax, __shfl_xor(tmax, 16));
        tmax = fmaxf(tmax, __shfl_xor(tmax, 32));
        if (!__all(tmax <= m_run + 8.f)) {      // T13 defer-max
            const float mnew = fmaxf(m_run, tmax);
            const float fac = __expf(m_run - mnew);
            l_run *= fac;
#pragma unroll
            for (int i = 0; i < 8; ++i) acco[i] *= fac;
            m_run = mnew;
        }
        float tsum = 0.f;
#pragma unroll
        for (int i = 0; i < 16; ++i) { p16[i] = __expf(p16[i] - m_run); tsum += p16[i]; }
        tsum += __shfl_xor(tsum, 16);
        tsum += __shfl_xor(tsum, 32);
        l_run += tsum;

        // P -> bf16 via v_cvt_pk_bf16_f32 (RNE), same element order as before
        u32x4 pw0, pw1;
#pragma unroll
        for (int wd = 0; wd < 4; ++wd) {
            unsigned r0, r1;
            asm("v_cvt_pk_bf16_f32 %0, %1, %2" : "=v"(r0) : "v"(p16[2 * wd]), "v"(p16[2 * wd + 1]));
            asm("v_cvt_pk_bf16_f32 %0, %1, %2" : "=v"(r1) : "v"(p16[8 + 2 * wd]), "v"(p16[8 + 2 * wd + 1]));
            pw0[wd] = r0; pw1[wd] = r1;
        }
        bf16x8 pb[2] = { __builtin_bit_cast(bf16x8, pw0), __builtin_bit_cast(bf16x8, pw1) };

        __builtin_amdgcn_s_setprio(1);
#pragma unroll
        for (int dc = 0; dc < 8; ++dc) {
            const int d = dc * 16 + n;
            const int swd = ((d >> 3) & 7) << 2;
#pragma unroll
            for (int k32 = 0; k32 < 2; ++k32) {
                bf16x4 g0 = *(const bf16x4*)&Vt[d * 72 + (k32 * 32 + ((4 * l4) ^ swd))];
                bf16x4 g1 = *(const bf16x4*)&Vt[d * 72 + (k32 * 32 + ((16 + 4 * l4) ^ swd))];
                bf16x8 vf = { g0[0], g0[1], g0[2], g0[3], g1[0], g1[1], g1[2], g1[3] };
                acco[dc] = __builtin_amdgcn_mfma_f32_16x16x32_bf16(vf, pb[k32], acco[dc], 0, 0, 0);
            }
        }
        __builtin_amdgcn_s_setprio(0);
    }

    __syncthreads();
    const float inv = 1.f / l_run;
#pragma unroll
    for (int dc = 0; dc < 8; ++dc)
#pragma unroll
        for (int r = 0; r < 4; ++r)
            Kl[(w * 16 + n) * 136 + dc * 16 + l4 * 4 + r] = f2bs(acco[dc][r] * inv);
    __syncthreads();
#pragma unroll
    for (int i = 0; i < 4; ++i) {
        const int row = i * 4 + (lane >> 4);
        const int col = (lane & 15) * 8;
        bf16x8 ov = *(const bf16x8*)&Kl[(w * 16 + row) * 136 + col];
        *(bf16x8*)&O[(long)(b * 1024 + qt * 64 + w * 16 + row) * 2048 + h * 128 + col] = ov;
    }
}

// ---------------------------------------------------------------------------
extern "C" void kernel_launch(void* const* d_in, const int* in_sizes, int n_in,
                              void* d_out, int out_size, void* d_ws, size_t ws_size,
                              hipStream_t stream) {
    const float* h   = (const float*)d_in[0];
    const float* Wq  = (const float*)d_in[1];
    const float* bq  = (const float*)d_in[2];
    const float* Wk  = (const float*)d_in[3];
    const float* bk  = (const float*)d_in[4];
    const float* Wv  = (const float*)d_in[5];
    const float* bv  = (const float*)d_in[6];
    const float* Wo  = (const float*)d_in[7];
    const float* bo  = (const float*)d_in[8];
    const void*  pkq = d_in[9];
    const float* pks = (const float*)d_in[10];
    const void*  pvq = d_in[11];
    const float* pvs = (const float*)d_in[12];
    float* out = (float*)d_out;

    char* ws = (char*)d_ws;
    dim3 blk(256);
    const bool big = (ws_size >= 75500000ull);

    if (big) {
        float* scal  = (float*)ws;
        short* hbf   = (short*)(ws + 256);                       // 8.4MB (reused as attn out)
        short* WT3   = (short*)(ws + 256 + 1L * 8388608);        // 25.2MB (3 transposed weights)
        short* Qbf   = (short*)(ws + 256 + 4L * 8388608);        // 8.4MB
        short* Kfull = (short*)(ws + 256 + 5L * 8388608);        // 16.8MB
        short* Vfull = (short*)(ws + 256 + 5L * 8388608 + 16777216);
        short* attnb = hbf;

        probe_init<<<1, 64, 0, stream>>>((const int*)pkq, scal);
        conv_bf16<<<1024, blk, 0, stream>>>(h, hbf);
        dequant_kernel<<<dim3(256, 1, 2), blk, 0, stream>>>(pkq, pvq, pks, pvs, Kfull, Vfull,
                                                            (const int*)d_ws);
        transpose_conv<<<dim3(32, 32, 3), blk, 0, stream>>>(Wq, Wk, Wv, WT3);
        gemm_m97<<<dim3(16, 16, 3), blk, 0, stream>>>(hbf, WT3, WT3 + 4194304, WT3 + 8388608,
                                                      bq, bk, bv, Qbf, Kfull, Vfull,
                                                      scal, 0, 1.f, -1);
        quantize_kernel<<<dim3(256, 1, 2), blk, 0, stream>>>(Kfull, Vfull, scal, out);
        attn_kernel<<<dim3(16, 16, 2), blk, 0, stream>>>(Qbf, Kfull, Vfull, attnb);
        transpose_conv<<<dim3(32, 32, 1), blk, 0, stream>>>(Wo, Wo, Wo, WT3);
        gemm_m97<<<dim3(16, 16, 1), blk, 0, stream>>>(attnb, WT3, WT3, WT3, bo, bo, bo,
                                                      out, out, out, scal, 0, 1.f, -1);
    } else {
        float* scal  = (float*)ws;
        short* hbf   = (short*)(ws + 256);
        short* WT    = (short*)(ws + 256 + 1L * 8388608);
        short* Qbf   = (short*)(ws + 256 + 2L * 8388608);
        short* Kfull = (short*)(ws + 256 + 3L * 8388608);
        short* Vfull = (short*)(ws + 256 + 3L * 8388608 + 16777216);
        short* attnb = hbf;

        probe_init<<<1, 64, 0, stream>>>((const int*)pkq, scal);
        conv_bf16<<<1024, blk, 0, stream>>>(h, hbf);
        dequant_kernel<<<dim3(256, 1, 2), blk, 0, stream>>>(pkq, pvq, pks, pvs, Kfull, Vfull,
                                                            (const int*)d_ws);
        transpose_conv<<<dim3(32, 32, 1), blk, 0, stream>>>(Wk, Wk, Wk, WT);
        gemm_m97<<<dim3(16, 16, 1), blk, 0, stream>>>(hbf, WT, WT, WT, bk, bk, bk,
                                                      Kfull, Kfull, Kfull, scal, 2, 1.f, 0);
        transpose_conv<<<dim3(32, 32, 1), blk, 0, stream>>>(Wv, Wv, Wv, WT);
        gemm_m97<<<dim3(16, 16, 1), blk, 0, stream>>>(hbf, WT, WT, WT, bv, bv, bv,
                                                      Vfull, Vfull, Vfull, scal, 2, 1.f, 1);
        quantize_kernel<<<dim3(256, 1, 2), blk, 0, stream>>>(Kfull, Vfull, scal, out);
        transpose_conv<<<dim3(32, 32, 1), blk, 0, stream>>>(Wq, Wq, Wq, WT);
        gemm_m97<<<dim3(16, 16, 1), blk, 0, stream>>>(hbf, WT, WT, WT, bq, bq, bq,
                                                      Qbf, Qbf, Qbf, scal, 1, SOFT_SCALE, -1);
        attn_kernel<<<dim3(16, 16, 2), blk, 0, stream>>>(Qbf, Kfull, Vfull, attnb);
        transpose_conv<<<dim3(32, 32, 1), blk, 0, stream>>>(Wo, Wo, Wo, WT);
        gemm_m97<<<dim3(16, 16, 1), blk, 0, stream>>>(attnb, WT, WT, WT, bo, bo, bo,
                                                      out, out, out, scal, 0, 1.f, -1);
    }
}